// Round 3
// baseline (456.863 us; speedup 1.0000x reference)
//
#include <hip/hip_runtime.h>

#define NPTS 150000
#define NHEAD 5
#define KTOT 1152
#define MTILES 1172   // ceil(150000/128)
#define EPSV 1e-5f

typedef __bf16 bf16x8 __attribute__((ext_vector_type(8)));
typedef float f32x4 __attribute__((ext_vector_type(4)));
typedef unsigned short u16x8 __attribute__((ext_vector_type(8)));

// ws layout (bytes):
//   xbf      @ 0          : 150016*128*2      = 38,404,096
//   w1t      @ 38404096   : 5*128*1152*2      =  1,474,560   (pre-swizzled B^T)
//   accw     @ 39878656   : 5*150000*128*2    = 192,000,000
//   partials @ 231878656  : 1172*1280*4       =  6,000,640
//   stats    @ 237879296  : 1280*4            =      5,120
#define WS_NEEDED 237884416UL

__device__ __forceinline__ unsigned short f2bf(float f) {
    unsigned int u = __float_as_uint(f);
    u += 0x7FFFu + ((u >> 16) & 1u);          // round-to-nearest-even
    return (unsigned short)(u >> 16);
}

__device__ __forceinline__ void gload16(const void* g, void* l) {
    __builtin_amdgcn_global_load_lds((const __attribute__((address_space(1))) void*)g,
                                     (__attribute__((address_space(3))) void*)l, 16, 0, 0);
}

// ---------------- pass 1: x (f32) -> bf16, plus zero pad row at index NPTS ----
__global__ void k_convert(const float* __restrict__ x, unsigned short* __restrict__ xbf) {
    const size_t i8 = (size_t)blockIdx.x * 256 + threadIdx.x;
    const size_t base = i8 * 8;
    if (base >= (size_t)(NPTS + 1) * 128) return;
    if (base < (size_t)NPTS * 128) {
        float4 v0 = *(const float4*)(x + base);
        float4 v1 = *(const float4*)(x + base + 4);
        u16x8 o;
        o[0] = f2bf(v0.x); o[1] = f2bf(v0.y); o[2] = f2bf(v0.z); o[3] = f2bf(v0.w);
        o[4] = f2bf(v1.x); o[5] = f2bf(v1.y); o[6] = f2bf(v1.z); o[7] = f2bf(v1.w);
        *(u16x8*)(xbf + base) = o;
    } else {
        u16x8 z = {0,0,0,0,0,0,0,0};
        *(u16x8*)(xbf + base) = z;
    }
}

// ---- pass 2: W1[h][k][c][d] -> w1t bf16 B^T with baked T2 swizzle ------------
__global__ void k_w1t(const float* __restrict__ W1, unsigned short* __restrict__ w1t) {
    const int idx = blockIdx.x * 256 + threadIdx.x;   // 737280 = 2880*256 exact
    const int d = idx & 127;
    const int c = (idx >> 7) & 127;
    const int hk = idx >> 14;           // h*9 + k
    const int k = hk % 9, h = hk / 9;
    const int col = h * 128 + d;
    const int p = k * 128 + c;
    const int j0 = (p >> 3) & 7;        // 16B block within 64-short segment
    const int jj = j0 ^ (col & 7);      // swizzled block position
    w1t[(size_t)col * KTOT + (p & ~63) + jj * 8 + (p & 7)] = f2bf(W1[idx]);
}

// ------- pass 3: gather-GEMM, counted-vmcnt pipeline + raw barriers ----------
__global__ __launch_bounds__(512, 2) void k_gemm(
    const unsigned short* __restrict__ xbf,
    const unsigned short* __restrict__ w1t,
    const int* __restrict__ nbr,
    unsigned short* __restrict__ accw,
    float* __restrict__ partials)
{
    __shared__ unsigned short A_lds[2][128 * 64];    // 32 KB (swizzled)
    __shared__ unsigned short B_lds[2][320 * 64];    // 80 KB (swizzled)
    __shared__ int nbr_s[9 * 128];
    __shared__ float stats_lds[640];

    const int tid = threadIdx.x;
    const int wid = tid >> 6;
    const int lane = tid & 63;
    const int bm = blockIdx.x;
    const int b2 = blockIdx.y;          // which 320-col half
    const int tile0 = bm * 128;

    for (int t = tid; t < 1152; t += 512) {
        const int k = t >> 7, r = t & 127;
        const int grow = tile0 + r;
        nbr_s[t] = (grow < NPTS) ? nbr[grow * 9 + k] : NPTS;
    }
    __syncthreads();

    const int RM = (wid >> 2) * 64;        // wave row base (0/64)
    const int CNl = (wid & 3) * 80;        // wave local-col base
    const int lr8 = lane >> 3;
    const int jlA = (lane & 7) ^ lr8;      // A: swizzled source 16B-block

    f32x4 acc[4][5];
#pragma unroll
    for (int m = 0; m < 4; m++)
#pragma unroll
        for (int n = 0; n < 5; n++) acc[m][n] = f32x4{0.f, 0.f, 0.f, 0.f};

    // stage one BK=64 K-tile (56 x 1KB segments, exactly 7 gloads per wave)
    auto stage = [&](int buf, int s) {
        const int kn = s >> 1;
        const int c0A = (s & 1) * 64 + jlA * 8;
#pragma unroll
        for (int j = 0; j < 7; ++j) {
            const int g = wid * 7 + j;                 // wave-uniform
            if (g < 16) {                              // A rows g*8..g*8+7
                const int r = g * 8 + lr8;
                const int idx = nbr_s[kn * 128 + r];
                gload16(xbf + (size_t)idx * 128 + c0A, &A_lds[buf][g * 512]);
            } else {                                   // B local cols
                const int lc = (g - 16) * 8 + lr8;
                gload16(w1t + (size_t)(b2 * 320 + lc) * KTOT + s * 64 + (lane & 7) * 8,
                        &B_lds[buf][(g - 16) * 512]);
            }
        }
    };

    stage(0, 0);
    stage(1, 1);                            // 14 loads/wave in flight

    for (int t = 0; t < 18; ++t) {
        const int b = t & 1;
        // B1: tile t staged (counted wait — stage(t+1) stays in flight)
        if (t < 17) asm volatile("s_waitcnt vmcnt(7)" ::: "memory");
        else        asm volatile("s_waitcnt vmcnt(0)" ::: "memory");
        asm volatile("s_barrier" ::: "memory");

        // move ALL fragments of tile t to registers (static indexing only)
        bf16x8 a[2][4], bfr[2][5];
#pragma unroll
        for (int kh = 0; kh < 2; ++kh) {
            const int jj = (kh * 4 + (lane >> 4)) ^ (lane & 7);
#pragma unroll
            for (int m = 0; m < 4; m++)
                a[kh][m] = *reinterpret_cast<const bf16x8*>(
                    &A_lds[b][(RM + m * 16 + (lane & 15)) * 64 + jj * 8]);
#pragma unroll
            for (int n = 0; n < 5; n++)
                bfr[kh][n] = *reinterpret_cast<const bf16x8*>(
                    &B_lds[b][(CNl + n * 16 + (lane & 15)) * 64 + jj * 8]);
        }
        asm volatile("s_waitcnt lgkmcnt(0)" ::: "memory");
        __builtin_amdgcn_sched_barrier(0);
        asm volatile("s_barrier" ::: "memory");   // B2: all waves done reading buf b

        if (t <= 15) stage(b, t + 2);             // overwrite buf b (frags in regs)

        __builtin_amdgcn_s_setprio(1);
#pragma unroll
        for (int kh = 0; kh < 2; ++kh)
#pragma unroll
            for (int n = 0; n < 5; n++)
#pragma unroll
                for (int m = 0; m < 4; m++)
                    acc[m][n] = __builtin_amdgcn_mfma_f32_16x16x32_bf16(a[kh][m], bfr[kh][n], acc[m][n], 0, 0, 0);
        __builtin_amdgcn_s_setprio(0);
    }

    // ---- epilogue: per-column sums/sumsq (deterministic partials) ----
    __syncthreads();                              // full drain before LDS reuse
    float sn[5], qn[5];
#pragma unroll
    for (int n = 0; n < 5; n++) {
        float s = 0.f, q = 0.f;
#pragma unroll
        for (int m = 0; m < 4; m++)
#pragma unroll
            for (int r = 0; r < 4; r++) { const float v = acc[m][n][r]; s += v; q += v * v; }
        s += __shfl_xor(s, 16); s += __shfl_xor(s, 32);
        q += __shfl_xor(q, 16); q += __shfl_xor(q, 32);
        sn[n] = s; qn[n] = q;
    }
    if (wid < 4 && lane < 16) {
#pragma unroll
        for (int n = 0; n < 5; n++) {
            const int lc = CNl + n * 16 + lane;
            stats_lds[lc] = sn[n];
            stats_lds[320 + lc] = qn[n];
        }
    }
    __syncthreads();
    if (wid >= 4 && lane < 16) {
#pragma unroll
        for (int n = 0; n < 5; n++) {
            const int lc = CNl + n * 16 + lane;
            stats_lds[lc] += sn[n];
            stats_lds[320 + lc] += qn[n];
        }
    }
    __syncthreads();
    for (int t = tid; t < 640; t += 512) {
        const int isq = (t >= 320);
        const int lc = isq ? (t - 320) : t;
        partials[(size_t)bm * 1280 + isq * 640 + b2 * 320 + lc] = stats_lds[t];
    }

    // ---- acc store (bf16), layout [h][n][d] ----
#pragma unroll
    for (int m = 0; m < 4; m++) {
        const int row0 = tile0 + RM + m * 16 + (lane >> 4) * 4;
#pragma unroll
        for (int n = 0; n < 5; n++) {
            const int gc = b2 * 320 + CNl + n * 16 + (lane & 15);
            const int hh = gc >> 7, d = gc & 127;
            unsigned short* bp = accw + (size_t)hh * NPTS * 128 + d;
#pragma unroll
            for (int r = 0; r < 4; r++) {
                const int rr = row0 + r;
                if (rr < NPTS) bp[(size_t)rr * 128] = f2bf(acc[m][n][r]);
            }
        }
    }
}

// ---------------- pass 4: finalize mean/rstd over 1172 partials ----------------
__global__ void k_stats(const float* __restrict__ partials, float* __restrict__ stats) {
    __shared__ float red[256];
    const int t = threadIdx.x;
    const int c0 = blockIdx.x * 32;
    const int half = (t >> 5) & 1;
    const int l32 = t & 31;
    const int chunk = t >> 6;
    const int off = half ? (640 + c0 + l32) : (c0 + l32);
    float v = 0.f;
    for (int b = chunk; b < MTILES; b += 4) v += partials[(size_t)b * 1280 + off];
    red[t] = v;
    __syncthreads();
    if (t < 64) red[t] = red[t] + red[t + 64] + red[t + 128] + red[t + 192];
    __syncthreads();
    if (t < 32) {
        const float s = red[t], q = red[t + 32];
        const float mean = s * (1.f / NPTS);
        const float var = q * (1.f / NPTS) - mean * mean;
        const float rstd = rsqrtf(var + EPSV);
        stats[c0 + t] = mean;
        stats[640 + c0 + t] = rstd;
    }
}

// ---------------- pass 5: normalize + relu + W2 + bias + mask ------------------
__global__ void k_out(const unsigned short* __restrict__ accw,
                      const float* __restrict__ stats,
                      const float* __restrict__ gamma, const float* __restrict__ beta,
                      const float* __restrict__ W2, const float* __restrict__ b2,
                      float* __restrict__ out) {
    __shared__ float sc[128], sh[128], w2s[384], b2s[3];
    const int h = blockIdx.y;
    const int t = threadIdx.x;
    if (t < 128) {
        const float mean = stats[h * 128 + t];
        const float rstd = stats[640 + h * 128 + t];
        const float g = gamma[h * 128 + t];
        const float bb = beta[h * 128 + t];
        sc[t] = rstd * g;
        sh[t] = bb - mean * rstd * g;
        w2s[t * 3 + 0] = W2[(h * 128 + t) * 3 + 0];
        w2s[t * 3 + 1] = W2[(h * 128 + t) * 3 + 1];
        w2s[t * 3 + 2] = W2[(h * 128 + t) * 3 + 2];
    }
    if (t < 3) b2s[t] = b2[h * 3 + t];
    __syncthreads();
    const int n = blockIdx.x * 256 + t;
    if (n >= NPTS) return;
    const u16x8* row = (const u16x8*)(accw + ((size_t)h * NPTS + n) * 128);
    float o0 = 0.f, o1 = 0.f, o2 = 0.f;
#pragma unroll
    for (int c8 = 0; c8 < 16; c8++) {
        const u16x8 v = row[c8];
#pragma unroll
        for (int j = 0; j < 8; j++) {
            const int c = c8 * 8 + j;
            const float a = __uint_as_float(((unsigned int)v[j]) << 16);
            const float hc = fmaxf(fmaf(a, sc[c], sh[c]), 0.f);
            o0 = fmaf(hc, w2s[c * 3 + 0], o0);
            o1 = fmaf(hc, w2s[c * 3 + 1], o1);
            o2 = fmaf(hc, w2s[c * 3 + 2], o2);
        }
    }
    const int noc = (h == 2) ? 1 : ((h == 1 || h == 4) ? 2 : 3);
    const size_t ob = ((size_t)h * NPTS + n) * 3;
    out[ob + 0] = (noc > 0) ? (o0 + b2s[0]) : 0.f;
    out[ob + 1] = (noc > 1) ? (o1 + b2s[1]) : 0.f;
    out[ob + 2] = (noc > 2) ? (o2 + b2s[2]) : 0.f;
}

__global__ void k_sentinel(float* __restrict__ out, int n) {
    const int i = blockIdx.x * 256 + threadIdx.x;
    if (i < n) out[i] = 12345.0f;
}

extern "C" void kernel_launch(void* const* d_in, const int* in_sizes, int n_in,
                              void* d_out, int out_size, void* d_ws, size_t ws_size,
                              hipStream_t stream) {
    const float* x     = (const float*)d_in[0];
    const int*   nbr   = (const int*)d_in[1];
    const float* W1    = (const float*)d_in[2];
    const float* gamma = (const float*)d_in[3];
    const float* beta  = (const float*)d_in[4];
    const float* W2    = (const float*)d_in[5];
    const float* b2    = (const float*)d_in[6];
    float* out = (float*)d_out;

    if (ws_size < WS_NEEDED) {
        k_sentinel<<<(out_size + 255) / 256, 256, 0, stream>>>(out, out_size);
        return;
    }

    char* ws = (char*)d_ws;
    unsigned short* xbf      = (unsigned short*)(ws);
    unsigned short* w1t      = (unsigned short*)(ws + 38404096);
    unsigned short* accw     = (unsigned short*)(ws + 39878656);
    float*          partials = (float*)(ws + 231878656);
    float*          stats    = (float*)(ws + 237879296);

    k_convert<<<9376, 256, 0, stream>>>(x, xbf);
    k_w1t<<<2880, 256, 0, stream>>>(W1, w1t);
    k_gemm<<<dim3(MTILES, 2), 512, 0, stream>>>(xbf, w1t, nbr, accw, partials);
    k_stats<<<20, 256, 0, stream>>>(partials, stats);
    k_out<<<dim3(586, 5), 256, 0, stream>>>(accw, stats, gamma, beta, W2, b2, out);
}

// Round 5
// 407.084 us; speedup vs baseline: 1.1223x; 1.1223x over previous
//
#include <hip/hip_runtime.h>

#define NPTS 150000
#define NHEAD 5
#define KTOT 1152
#define NTILES 1172   // ceil(150000/128)
#define NBLK 586      // ceil(150000/256)
#define EPSV 1e-5f

typedef __bf16 bf16x8 __attribute__((ext_vector_type(8)));
typedef float f32x4 __attribute__((ext_vector_type(4)));
typedef unsigned short u16x8 __attribute__((ext_vector_type(8)));

// ws layout (bytes):
//   xbf      @ 0          : 150016*128*2      = 38,404,096
//   w1t      @ 38404096   : 5*128*1152*2      =  1,474,560   (pre-swizzled B^T)
//   accw     @ 39878656   : 5*150000*128*2    = 192,000,000
//     (hist @ accw+0 : 586*512*4 = 1,200,128 ; off @ accw+2,097,152 — both pre-GEMM only)
//   partials @ 231878656  : 1172*1280*4       =  6,000,640
//   stats    @ 237879296  : 1280*4            =      5,120
//   perm     @ 237884416  : 150000*4          =    600,000
#define WS_NEEDED 238484416UL

__device__ __forceinline__ unsigned short f2bf(float f) {
    unsigned int u = __float_as_uint(f);
    u += 0x7FFFu + ((u >> 16) & 1u);          // round-to-nearest-even
    return (unsigned short)(u >> 16);
}

__device__ __forceinline__ void gload16(const void* g, void* l) {
    __builtin_amdgcn_global_load_lds((const __attribute__((address_space(1))) void*)g,
                                     (__attribute__((address_space(3))) void*)l, 16, 0, 0);
}

// ---------------- pass 1: x (f32) -> bf16, plus zero pad row at index NPTS ----
__global__ void k_convert(const float* __restrict__ x, unsigned short* __restrict__ xbf) {
    const size_t i8 = (size_t)blockIdx.x * 256 + threadIdx.x;
    const size_t base = i8 * 8;
    if (base >= (size_t)(NPTS + 1) * 128) return;
    if (base < (size_t)NPTS * 128) {
        float4 v0 = *(const float4*)(x + base);
        float4 v1 = *(const float4*)(x + base + 4);
        u16x8 o;
        o[0] = f2bf(v0.x); o[1] = f2bf(v0.y); o[2] = f2bf(v0.z); o[3] = f2bf(v0.w);
        o[4] = f2bf(v1.x); o[5] = f2bf(v1.y); o[6] = f2bf(v1.z); o[7] = f2bf(v1.w);
        *(u16x8*)(xbf + base) = o;
    } else {
        u16x8 z = {0,0,0,0,0,0,0,0};
        *(u16x8*)(xbf + base) = z;
    }
}

// ---- pass 2: W1[h][k][c][d] -> w1t bf16 B^T with baked T2 swizzle ------------
__global__ void k_w1t(const float* __restrict__ W1, unsigned short* __restrict__ w1t) {
    const int idx = blockIdx.x * 256 + threadIdx.x;   // 737280 = 2880*256 exact
    const int d = idx & 127;
    const int c = (idx >> 7) & 127;
    const int hk = idx >> 14;           // h*9 + k
    const int k = hk % 9, h = hk / 9;
    const int col = h * 128 + d;
    const int p = k * 128 + c;
    const int j0 = (p >> 3) & 7;
    const int jj = j0 ^ (col & 7);
    w1t[(size_t)col * KTOT + (p & ~63) + jj * 8 + (p & 7)] = f2bf(W1[idx]);
}

// ---- sort pass A: per-block histogram of 9-bit validity patterns -------------
__global__ void k_hist(const int* __restrict__ nbr, int* __restrict__ hist) {
    __shared__ int lh[512];
    const int t = threadIdx.x, b = blockIdx.x;
    lh[t] = 0; lh[t + 256] = 0;
    __syncthreads();
    const int n = b * 256 + t;
    if (n < NPTS) {
        int pat = 0;
#pragma unroll
        for (int k = 0; k < 9; k++) pat |= (nbr[n * 9 + k] != NPTS) << k;
        atomicAdd(&lh[pat], 1);
    }
    __syncthreads();
    hist[b * 512 + t] = lh[t];
    hist[b * 512 + t + 256] = lh[t + 256];
}

// ---- sort pass B: offsets (deterministic serial scan) ------------------------
__global__ void k_off(const int* __restrict__ hist, int* __restrict__ off) {
    __shared__ int tot[512];
    const int k = threadIdx.x;
    int s = 0;
    for (int b = 0; b < NBLK; b++) s += hist[b * 512 + k];
    tot[k] = s;
    __syncthreads();
    if (k == 0) { int run = 0; for (int i = 0; i < 512; i++) { int v = tot[i]; tot[i] = run; run += v; } }
    __syncthreads();
    int run = tot[k];
    for (int b = 0; b < NBLK; b++) { off[b * 512 + k] = run; run += hist[b * 512 + k]; }
}

// ---- sort pass C: stable rank-scatter into perm ------------------------------
__global__ void k_scatter(const int* __restrict__ nbr, const int* __restrict__ off,
                          int* __restrict__ perm) {
    __shared__ int pat_s[256];
    const int t = threadIdx.x, b = blockIdx.x;
    const int n = b * 256 + t;
    int pat = -1;
    if (n < NPTS) {
        pat = 0;
#pragma unroll
        for (int k = 0; k < 9; k++) pat |= (nbr[n * 9 + k] != NPTS) << k;
    }
    pat_s[t] = pat;
    __syncthreads();
    if (n < NPTS) {
        int rank = 0;
        for (int j = 0; j < 256; j++) rank += (j < t) & (pat_s[j] == pat);
        perm[off[b * 512 + pat] + rank] = n;
    }
}

// ------- pass 3: sparse gather-GEMM over valid k only (R2 pipeline) -----------
__global__ __launch_bounds__(512, 2) void k_gemm(
    const unsigned short* __restrict__ xbf,
    const unsigned short* __restrict__ w1t,
    const int* __restrict__ nbr,
    const int* __restrict__ perm,
    unsigned short* __restrict__ accw,
    float* __restrict__ partials)
{
    __shared__ unsigned short ABC[57344];  // A:[2][8192]@0, B:[2][20480]@16384; C aliases @0
    __shared__ int nbr_s[9 * 128];
    __shared__ int perm_s[128];
    __shared__ int mask_s;
    __shared__ float stats_lds[640];

    const int tid = threadIdx.x;
    const int wid = tid >> 6;
    const int lane = tid & 63;
    const int bm = blockIdx.x;
    const int b2 = blockIdx.y;
    const int tile = (bm * 331) % NTILES;   // spread heavy tiles across rounds
    const int tile0 = tile * 128;

    if (tid == 0) mask_s = 0;
    if (tid < 128) {
        const int gr = tile0 + tid;
        perm_s[tid] = (gr < NPTS) ? perm[gr] : NPTS;
    }
    __syncthreads();
    {
        const int r = tid & 127;
        const int prow = perm_s[r];
        for (int k = tid >> 7; k < 9; k += 4)
            nbr_s[k * 128 + r] = (prow < NPTS) ? nbr[prow * 9 + k] : NPTS;
    }
    __syncthreads();
    if (tid < 128) {
        int pat = 0;
#pragma unroll
        for (int k = 0; k < 9; k++) pat |= (nbr_s[k * 128 + tid] != NPTS) << k;
        if (pat) atomicOr(&mask_s, pat);
    }
    __syncthreads();
    const int mask = mask_s;                     // block-uniform, bit4 always set
    const int steps = 2 * __builtin_popcount(mask);

    const int RM = (wid >> 2) * 64;
    const int CNl = (wid & 3) * 80;
    const int lr8 = lane >> 3;
    const int jlA = (lane & 7) ^ lr8;

    f32x4 acc[4][5];
#pragma unroll
    for (int m = 0; m < 4; m++)
#pragma unroll
        for (int n = 0; n < 5; n++) acc[m][n] = f32x4{0.f, 0.f, 0.f, 0.f};

    auto stage = [&](int buf, int step) {        // step = kn*2 + half
        const int kn = step >> 1;
        const int c0A = (step & 1) * 64 + jlA * 8;
#pragma unroll
        for (int j = 0; j < 7; ++j) {
            const int g = wid * 7 + j;
            if (g < 16) {
                const int r = g * 8 + lr8;
                const int idx = nbr_s[kn * 128 + r];
                gload16(xbf + (size_t)idx * 128 + c0A, (void*)(ABC + buf * 8192 + g * 512));
            } else {
                const int lc = (g - 16) * 8 + lr8;
                gload16(w1t + (size_t)(b2 * 320 + lc) * KTOT + step * 64 + (lane & 7) * 8,
                        (void*)(ABC + 16384 + buf * 20480 + (g - 16) * 512));
            }
        }
    };

    auto compute = [&](int buf) {
        const unsigned short* Ab = ABC + buf * 8192;
        const unsigned short* Bb = ABC + 16384 + buf * 20480;
#pragma unroll
        for (int kh = 0; kh < 2; ++kh) {
            const int jj = (kh * 4 + (lane >> 4)) ^ (lane & 7);
            bf16x8 a[4];
#pragma unroll
            for (int m = 0; m < 4; m++)
                a[m] = *reinterpret_cast<const bf16x8*>(&Ab[(RM + m * 16 + (lane & 15)) * 64 + jj * 8]);
#pragma unroll
            for (int n = 0; n < 5; n++) {
                const bf16x8 b = *reinterpret_cast<const bf16x8*>(&Bb[(CNl + n * 16 + (lane & 15)) * 64 + jj * 8]);
#pragma unroll
                for (int m = 0; m < 4; m++)
                    acc[m][n] = __builtin_amdgcn_mfma_f32_16x16x32_bf16(a[m], b, acc[m][n], 0, 0, 0);
            }
        }
    };

    // walk set bits of mask: (kn,0),(kn,1),(kn',0),...  — R2 pipeline structure
    int ckn = __builtin_ctz(mask), ch = 0, rem = mask & (mask - 1), buf = 0;
    stage(0, ckn * 2);
    __syncthreads();
    for (int i = 0; i < steps; i++) {
        int nkn, nh, nrem;
        if (ch == 0) { nkn = ckn; nh = 1; nrem = rem; }
        else { nkn = rem ? __builtin_ctz(rem) : 0; nh = 0; nrem = rem & (rem - 1); }
        if (i + 1 < steps) stage(buf ^ 1, nkn * 2 + nh);
        compute(buf);
        __syncthreads();
        ckn = nkn; ch = nh; rem = nrem; buf ^= 1;
    }

    // ---- per-column sums/sumsq (deterministic partials) ----
    float sn[5], qn[5];
#pragma unroll
    for (int n = 0; n < 5; n++) {
        float s = 0.f, q = 0.f;
#pragma unroll
        for (int m = 0; m < 4; m++)
#pragma unroll
            for (int r = 0; r < 4; r++) { const float v = acc[m][n][r]; s += v; q += v * v; }
        s += __shfl_xor(s, 16); s += __shfl_xor(s, 32);
        q += __shfl_xor(q, 16); q += __shfl_xor(q, 32);
        sn[n] = s; qn[n] = q;
    }
    if (wid < 4 && lane < 16) {
#pragma unroll
        for (int n = 0; n < 5; n++) {
            const int lc = CNl + n * 16 + lane;
            stats_lds[lc] = sn[n];
            stats_lds[320 + lc] = qn[n];
        }
    }
    __syncthreads();
    if (wid >= 4 && lane < 16) {
#pragma unroll
        for (int n = 0; n < 5; n++) {
            const int lc = CNl + n * 16 + lane;
            stats_lds[lc] += sn[n];
            stats_lds[320 + lc] += qn[n];
        }
    }
    __syncthreads();
    for (int t = tid; t < 640; t += 512) {
        const int isq = (t >= 320);
        const int lc = isq ? (t - 320) : t;
        partials[(size_t)bm * 1280 + isq * 640 + b2 * 320 + lc] = stats_lds[t];
    }

    // ---- C store via LDS transpose: coalesced 16B stores ----
    unsigned short* C = (unsigned short*)ABC;    // 128 x 328 (padded)
#pragma unroll
    for (int m = 0; m < 4; m++) {
        const int row = RM + m * 16 + (lane >> 4) * 4;
#pragma unroll
        for (int n = 0; n < 5; n++) {
            const int col = CNl + n * 16 + (lane & 15);
#pragma unroll
            for (int r = 0; r < 4; r++)
                C[(row + r) * 328 + col] = f2bf(acc[m][n][r]);
        }
    }
    __syncthreads();
#pragma unroll
    for (int j = 0; j < 10; j++) {
        const int chunk = tid + 512 * j;         // 5120 chunks = 128 rows x 40 chunks
        const int row = chunk / 40, cc = chunk % 40;
        const int prow = perm_s[row];
        if (prow < NPTS) {
            const int col = b2 * 320 + cc * 8;
            const int hh = col >> 7, d = col & 127;
            *(u16x8*)(accw + ((size_t)hh * NPTS + prow) * 128 + d) =
                *(const u16x8*)&C[row * 328 + cc * 8];
        }
    }
}

// ---------------- pass 4: finalize mean/rstd over 1172 partials ----------------
__global__ void k_stats(const float* __restrict__ partials, float* __restrict__ stats) {
    __shared__ float red[256];
    const int t = threadIdx.x;
    const int c0 = blockIdx.x * 32;
    const int half = (t >> 5) & 1;
    const int l32 = t & 31;
    const int chunk = t >> 6;
    const int off = half ? (640 + c0 + l32) : (c0 + l32);
    float v = 0.f;
    for (int b = chunk; b < NTILES; b += 4) v += partials[(size_t)b * 1280 + off];
    red[t] = v;
    __syncthreads();
    if (t < 64) red[t] = red[t] + red[t + 64] + red[t + 128] + red[t + 192];
    __syncthreads();
    if (t < 32) {
        const float s = red[t], q = red[t + 32];
        const float mean = s * (1.f / NPTS);
        const float var = q * (1.f / NPTS) - mean * mean;
        const float rstd = rsqrtf(var + EPSV);
        stats[c0 + t] = mean;
        stats[640 + c0 + t] = rstd;
    }
}

// ---------------- pass 5: normalize + relu + W2 + bias + mask ------------------
__global__ void k_out(const unsigned short* __restrict__ accw,
                      const float* __restrict__ stats,
                      const float* __restrict__ gamma, const float* __restrict__ beta,
                      const float* __restrict__ W2, const float* __restrict__ b2,
                      float* __restrict__ out) {
    __shared__ float sc[128], sh[128], w2s[384], b2s[3];
    const int h = blockIdx.y;
    const int t = threadIdx.x;
    if (t < 128) {
        const float mean = stats[h * 128 + t];
        const float rstd = stats[640 + h * 128 + t];
        const float g = gamma[h * 128 + t];
        const float bb = beta[h * 128 + t];
        sc[t] = rstd * g;
        sh[t] = bb - mean * rstd * g;
        w2s[t * 3 + 0] = W2[(h * 128 + t) * 3 + 0];
        w2s[t * 3 + 1] = W2[(h * 128 + t) * 3 + 1];
        w2s[t * 3 + 2] = W2[(h * 128 + t) * 3 + 2];
    }
    if (t < 3) b2s[t] = b2[h * 3 + t];
    __syncthreads();
    const int n = blockIdx.x * 256 + t;
    if (n >= NPTS) return;
    const u16x8* row = (const u16x8*)(accw + ((size_t)h * NPTS + n) * 128);
    float o0 = 0.f, o1 = 0.f, o2 = 0.f;
#pragma unroll
    for (int c8 = 0; c8 < 16; c8++) {
        const u16x8 v = row[c8];
#pragma unroll
        for (int j = 0; j < 8; j++) {
            const int c = c8 * 8 + j;
            const float a = __uint_as_float(((unsigned int)v[j]) << 16);
            const float hc = fmaxf(fmaf(a, sc[c], sh[c]), 0.f);
            o0 = fmaf(hc, w2s[c * 3 + 0], o0);
            o1 = fmaf(hc, w2s[c * 3 + 1], o1);
            o2 = fmaf(hc, w2s[c * 3 + 2], o2);
        }
    }
    const int noc = (h == 2) ? 1 : ((h == 1 || h == 4) ? 2 : 3);
    const size_t ob = ((size_t)h * NPTS + n) * 3;
    out[ob + 0] = (noc > 0) ? (o0 + b2s[0]) : 0.f;
    out[ob + 1] = (noc > 1) ? (o1 + b2s[1]) : 0.f;
    out[ob + 2] = (noc > 2) ? (o2 + b2s[2]) : 0.f;
}

__global__ void k_sentinel(float* __restrict__ out, int n) {
    const int i = blockIdx.x * 256 + threadIdx.x;
    if (i < n) out[i] = 12345.0f;
}

extern "C" void kernel_launch(void* const* d_in, const int* in_sizes, int n_in,
                              void* d_out, int out_size, void* d_ws, size_t ws_size,
                              hipStream_t stream) {
    const float* x     = (const float*)d_in[0];
    const int*   nbr   = (const int*)d_in[1];
    const float* W1    = (const float*)d_in[2];
    const float* gamma = (const float*)d_in[3];
    const float* beta  = (const float*)d_in[4];
    const float* W2    = (const float*)d_in[5];
    const float* b2    = (const float*)d_in[6];
    float* out = (float*)d_out;

    if (ws_size < WS_NEEDED) {
        k_sentinel<<<(out_size + 255) / 256, 256, 0, stream>>>(out, out_size);
        return;
    }

    char* ws = (char*)d_ws;
    unsigned short* xbf      = (unsigned short*)(ws);
    unsigned short* w1t      = (unsigned short*)(ws + 38404096);
    unsigned short* accw     = (unsigned short*)(ws + 39878656);
    int*            hist     = (int*)(ws + 39878656);            // aliases accw (pre-GEMM)
    int*            off      = (int*)(ws + 39878656 + 2097152);  // aliases accw (pre-GEMM)
    float*          partials = (float*)(ws + 231878656);
    float*          stats    = (float*)(ws + 237879296);
    int*            perm     = (int*)(ws + 237884416);

    k_convert<<<9376, 256, 0, stream>>>(x, xbf);
    k_w1t<<<2880, 256, 0, stream>>>(W1, w1t);
    k_hist<<<NBLK, 256, 0, stream>>>(nbr, hist);
    k_off<<<1, 512, 0, stream>>>(hist, off);
    k_scatter<<<NBLK, 256, 0, stream>>>(nbr, off, perm);
    k_gemm<<<dim3(NTILES, 2), 512, 0, stream>>>(xbf, w1t, nbr, perm, accw, partials);
    k_stats<<<20, 256, 0, stream>>>(partials, stats);
    k_out<<<dim3(586, 5), 256, 0, stream>>>(accw, stats, gamma, beta, W2, b2, out);
}